// Round 6
// baseline (91.619 us; speedup 1.0000x reference)
//
#include <hip/hip_runtime.h>
#include <math.h>

#define N_DIM 64
#define TILE  128

typedef unsigned short ushort_t;
typedef unsigned int   uint_t;
typedef _Float16 f16x8 __attribute__((ext_vector_type(8)));
typedef _Float16 f16x4 __attribute__((ext_vector_type(4)));
typedef float    f32x4 __attribute__((ext_vector_type(4)));

// ---------------------------------------------------------------------------
// Prep: X -> fp16(x/l) row-major [N][64] (128 B/row) + exact fp32 row norms.
// ---------------------------------------------------------------------------
__global__ __launch_bounds__(256)
void matern52_prep_kernel(const float* __restrict__ X,
                          const float* __restrict__ l,
                          unsigned char* __restrict__ dst,
                          float* __restrict__ sq, int N)
{
    const int t   = threadIdx.x;
    const int kq  = t & 15;
    const int row = blockIdx.x * 16 + (t >> 4);

    float4 lv = *reinterpret_cast<const float4*>(&l[kq * 4]);
    float4 x  = *reinterpret_cast<const float4*>(&X[(size_t)row * N_DIM + kq * 4]);
    const float a0 = x.x / lv.x, a1 = x.y / lv.y, a2 = x.z / lv.z, a3 = x.w / lv.w;

    float s = a0 * a0;
    s = fmaf(a1, a1, s); s = fmaf(a2, a2, s); s = fmaf(a3, a3, s);
    s += __shfl_xor(s, 1);
    s += __shfl_xor(s, 2);
    s += __shfl_xor(s, 4);
    s += __shfl_xor(s, 8);
    if (kq == 0) sq[row] = s;

    f16x4 h = { (_Float16)a0, (_Float16)a1, (_Float16)a2, (_Float16)a3 };
    *reinterpret_cast<f16x4*>(dst + (size_t)row * 128 + kq * 8) = h;
}

// ---------------------------------------------------------------------------
// Main: 256 thr = 4 independent waves (2x2 quadrants of a 128x128 tile).
// NO LDS, NO barriers: each wave gathers its MFMA fragments straight from the
// L1/L2-hot fp16 workspace into VGPRs (16 x dwordx4 per lane), one K=64 fp16
// MFMA pass (operand-swapped: reg idx -> out col, lane&15 -> out row; verified
// r2-r5), matern epilogue, NON-TEMPORAL dwordx4 stores (don't write-allocate
// L2 -> keeps ws resident, fill-kernel store behavior).
// ---------------------------------------------------------------------------
__global__ __launch_bounds__(256, 4)
void matern52_main_kernel(const unsigned char* __restrict__ A16,
                          const unsigned char* __restrict__ B16,
                          const float* __restrict__ sq1,
                          const float* __restrict__ sq2,
                          const float* __restrict__ cc,
                          float* __restrict__ out,
                          int N1, int N2)
{
    const int t    = threadIdx.x;
    const int bi   = blockIdx.y, bj = blockIdx.x;
    const int wid  = t >> 6;          // 0..3
    const int lane = t & 63;
    const int wtr  = wid >> 1;        // 0..1 : 64-row strip
    const int wtc  = wid & 1;         // 0..1 : 64-col strip
    const int fr   = lane & 15;
    const int kg   = lane >> 4;

    // Per-lane fragment base pointers: row stride 128 B, chunk = kg*16.
    const unsigned char* pa =
        A16 + (size_t)bi * (TILE * 128) + ((wtr * 64 + fr) << 7) + (kg << 4);
    const unsigned char* pb =
        B16 + (size_t)bj * (TILE * 128) + ((wtc * 64 + fr) << 7) + (kg << 4);

    f32x4 acc[4][4] = {};

    #pragma unroll
    for (int kk = 0; kk < 2; ++kk) {
        f16x8 af[4], bg[4];
        #pragma unroll
        for (int m = 0; m < 4; ++m)
            af[m] = *reinterpret_cast<const f16x8*>(pa + m * 2048 + kk * 64);
        #pragma unroll
        for (int n = 0; n < 4; ++n)
            bg[n] = *reinterpret_cast<const f16x8*>(pb + n * 2048 + kk * 64);
        #pragma unroll
        for (int m = 0; m < 4; ++m)
            #pragma unroll
            for (int n = 0; n < 4; ++n)
                acc[m][n] = __builtin_amdgcn_mfma_f32_16x16x32_f16(
                    bg[n], af[m], acc[m][n], 0, 0, 0);
    }

    // ---- epilogue: out = poly(r,d2) * 2^(log2(c^2) - s5*log2e * r) ----------
    const float c0 = cc[0];
    const float SQ5   = 2.23606797749979f;
    const float FIVE3 = 1.66666666666667f;
    const float NK    = -3.22617785847899f;               // -sqrt5 * log2(e)
    const float l2c2  = 2.885390081777927f * __logf(c0);  // 2*log2(c0)

    const float* sqA = sq1 + bi * TILE;
    const float* sqB = sq2 + bj * TILE + wtc * 64;

    #pragma unroll
    for (int m = 0; m < 4; ++m) {
        const int row_l = wtr * 64 + m * 16 + fr;
        const float sa = sqA[row_l];
        float* rowp = out + ((size_t)(bi * TILE) + row_l) * (size_t)N2
                          + (size_t)(bj * TILE) + wtc * 64;
        #pragma unroll
        for (int n = 0; n < 4; ++n) {
            const int cb = n * 16 + kg * 4;
            f32x4 sb4 = *reinterpret_cast<const f32x4*>(sqB + cb);
            f32x4 v = acc[m][n];
            f32x4 res;
            #pragma unroll
            for (int q = 0; q < 4; ++q) {
                float d2 = fmaxf(fmaf(-2.0f, v[q], sa + sb4[q]), 0.0f);
                float r  = __builtin_amdgcn_sqrtf(d2);               // raw v_sqrt_f32
                float e  = __builtin_amdgcn_exp2f(fmaf(NK, r, l2c2)); // raw v_exp_f32
                res[q] = fmaf(FIVE3, d2, fmaf(SQ5, r, 1.0f)) * e;
            }
            __builtin_nontemporal_store(res, reinterpret_cast<f32x4*>(rowp + cb));
        }
    }
}

// ---------------------------------------------------------------------------
// Fallback (ws too small): self-contained split-bf16 (round-3 verified).
// ---------------------------------------------------------------------------
__device__ __forceinline__ ushort_t f2bf(float f) {
    uint_t u = __float_as_uint(f);
    u += 0x7FFFu + ((u >> 16) & 1u);
    return (ushort_t)(u >> 16);
}
__device__ __forceinline__ float bf2f(ushort_t h) {
    return __uint_as_float(((uint_t)h) << 16);
}
typedef short s16x8 __attribute__((ext_vector_type(8)));

__device__ __forceinline__ int swz16(int row, int kc) {
    return (row << 7) + ((kc ^ (row & 7)) << 4);
}

__global__ __launch_bounds__(512, 4)
void matern52_fallback_kernel(const float* __restrict__ X1,
                              const float* __restrict__ X2,
                              const float* __restrict__ cc,
                              const float* __restrict__ l,
                              float* __restrict__ out,
                              int N1, int N2)
{
    __shared__ ushort_t Ah[TILE * N_DIM], Al[TILE * N_DIM];
    __shared__ ushort_t Bh[TILE * N_DIM], Bl[TILE * N_DIM];
    __shared__ float sqA[TILE], sqB[TILE];

    const int t  = threadIdx.x;
    const int bi = blockIdx.y, bj = blockIdx.x;
    const int kq   = t & 15;
    const int rsub = t >> 4;

    float4 lv = *reinterpret_cast<const float4*>(&l[kq * 4]);
    const float rlx = 1.f / lv.x, rly = 1.f / lv.y, rlz = 1.f / lv.z, rlw = 1.f / lv.w;
    const float* x1b = X1 + (size_t)(bi * TILE) * N_DIM;
    const float* x2b = X2 + (size_t)(bj * TILE) * N_DIM;

    #define STAGE(Xb, Th, Tl, SQ)                                              \
    {                                                                          \
        _Pragma("unroll")                                                      \
        for (int c = 0; c < 4; ++c) {                                          \
            const int row = c * 32 + rsub;                                     \
            float4 x = *reinterpret_cast<const float4*>(&(Xb)[row * N_DIM + kq * 4]); \
            float a0 = x.x * rlx, a1 = x.y * rly, a2 = x.z * rlz, a3 = x.w * rlw; \
            ushort_t h0 = f2bf(a0), h1 = f2bf(a1), h2 = f2bf(a2), h3 = f2bf(a3); \
            ushort_t e0 = f2bf(a0 - bf2f(h0)), e1 = f2bf(a1 - bf2f(h1));       \
            ushort_t e2 = f2bf(a2 - bf2f(h2)), e3 = f2bf(a3 - bf2f(h3));       \
            const int off = (row << 7) + (((kq >> 1) << 4) ^ ((row & 7) << 4)) + ((kq & 1) << 3); \
            uint2 hv, lvv;                                                     \
            hv.x  = (uint_t)h0 | ((uint_t)h1 << 16);                           \
            hv.y  = (uint_t)h2 | ((uint_t)h3 << 16);                           \
            lvv.x = (uint_t)e0 | ((uint_t)e1 << 16);                           \
            lvv.y = (uint_t)e2 | ((uint_t)e3 << 16);                           \
            *reinterpret_cast<uint2*>((char*)(Th) + off) = hv;                 \
            *reinterpret_cast<uint2*>((char*)(Tl) + off) = lvv;                \
            float s = a0 * a0;                                                 \
            s = fmaf(a1, a1, s); s = fmaf(a2, a2, s); s = fmaf(a3, a3, s);     \
            s += __shfl_xor(s, 1);                                             \
            s += __shfl_xor(s, 2);                                             \
            s += __shfl_xor(s, 4);                                             \
            s += __shfl_xor(s, 8);                                             \
            if (kq == 0) (SQ)[row] = s;                                        \
        }                                                                      \
    }
    STAGE(x1b, Ah, Al, sqA)
    STAGE(x2b, Bh, Bl, sqB)
    #undef STAGE
    __syncthreads();

    const int wid  = t >> 6;
    const int lane = t & 63;
    const int wtr = wid >> 1, wtc = wid & 1;
    const int fr  = lane & 15, kg = lane >> 4;

    f32x4 acc[2][4] = {};
    #pragma unroll
    for (int pass = 0; pass < 3; ++pass) {
        const ushort_t* TA = (pass == 2) ? Al : Ah;
        const ushort_t* TB = (pass == 1) ? Bl : Bh;
        #pragma unroll
        for (int kk = 0; kk < 2; ++kk) {
            s16x8 af[2], bg[4];
            #pragma unroll
            for (int m = 0; m < 2; ++m)
                af[m] = *reinterpret_cast<const s16x8*>(
                    (const char*)TA + swz16(wtr * 32 + m * 16 + fr, kk * 4 + kg));
            #pragma unroll
            for (int n = 0; n < 4; ++n)
                bg[n] = *reinterpret_cast<const s16x8*>(
                    (const char*)TB + swz16(wtc * 64 + n * 16 + fr, kk * 4 + kg));
            #pragma unroll
            for (int m = 0; m < 2; ++m)
                #pragma unroll
                for (int n = 0; n < 4; ++n)
                    acc[m][n] = __builtin_amdgcn_mfma_f32_16x16x32_bf16(
                        bg[n], af[m], acc[m][n], 0, 0, 0);
        }
    }

    const float c0 = cc[0];
    const float SQ5   = 2.23606797749979f;
    const float FIVE3 = 1.66666666666667f;
    const float lnc2  = 2.0f * __logf(c0);

    #pragma unroll
    for (int m = 0; m < 2; ++m) {
        const int row_l = wtr * 32 + m * 16 + fr;
        const float sa = sqA[row_l];
        float* rowp = out + ((size_t)(bi * TILE) + row_l) * (size_t)N2
                          + (size_t)(bj * TILE) + wtc * 64;
        #pragma unroll
        for (int n = 0; n < 4; ++n) {
            const int cb = n * 16 + kg * 4;
            f32x4 sb4 = *reinterpret_cast<const f32x4*>(&sqB[wtc * 64 + cb]);
            f32x4 v = acc[m][n];
            f32x4 res;
            #pragma unroll
            for (int q = 0; q < 4; ++q) {
                float d2 = fmaxf(fmaf(-2.0f, v[q], sa + sb4[q]), 0.0f);
                float r  = sqrtf(d2);
                float e  = __expf(fmaf(-SQ5, r, lnc2));
                res[q] = fmaf(FIVE3, d2, fmaf(SQ5, r, 1.0f)) * e;
            }
            *reinterpret_cast<f32x4*>(rowp + cb) = res;
        }
    }
}

extern "C" void kernel_launch(void* const* d_in, const int* in_sizes, int n_in,
                              void* d_out, int out_size, void* d_ws, size_t ws_size,
                              hipStream_t stream) {
    const float* X1 = (const float*)d_in[0];
    const float* X2 = (const float*)d_in[1];
    const float* c  = (const float*)d_in[2];
    const float* l  = (const float*)d_in[3];
    float* out = (float*)d_out;

    const int N1 = in_sizes[0] / N_DIM;   // 8192
    const int N2 = in_sizes[1] / N_DIM;   // 8192

    const size_t aBytes = (size_t)N1 * 128;
    const size_t bBytes = (size_t)N2 * 128;
    const size_t needWs = aBytes + bBytes + (size_t)(N1 + N2) * sizeof(float);

    dim3 grid(N2 / TILE, N1 / TILE);      // 64 x 64 blocks

    if (ws_size >= needWs) {
        unsigned char* A16 = (unsigned char*)d_ws;
        unsigned char* B16 = A16 + aBytes;
        float* sq1 = (float*)(B16 + bBytes);
        float* sq2 = sq1 + N1;

        matern52_prep_kernel<<<dim3(N1 / 16), 256, 0, stream>>>(X1, l, A16, sq1, N1);
        matern52_prep_kernel<<<dim3(N2 / 16), 256, 0, stream>>>(X2, l, B16, sq2, N2);
        matern52_main_kernel<<<grid, 256, 0, stream>>>(A16, B16, sq1, sq2, c, out, N1, N2);
    } else {
        matern52_fallback_kernel<<<grid, 512, 0, stream>>>(X1, X2, c, l, out, N1, N2);
    }
}

// Round 8
// 64.702 us; speedup vs baseline: 1.4160x; 1.4160x over previous
//
#include <hip/hip_runtime.h>
#include <math.h>

#define N_DIM 64
#define TILE  128     // fallback tile
#define BM    256     // main: rows per block (A panel)
#define BN    128     // main: cols per tile
#define NTJ   4       // tiles per block (consecutive bj)

typedef unsigned short ushort_t;
typedef unsigned int   uint_t;
typedef _Float16 f16x8 __attribute__((ext_vector_type(8)));
typedef _Float16 f16x4 __attribute__((ext_vector_type(4)));
typedef float    f32x4 __attribute__((ext_vector_type(4)));

// Byte offset of 16B chunk kc (0..7) in row `row` of a [rows x 128B] tile,
// XOR-swizzled (G4): spreads 8 consecutive rows' same-kc chunks over 8 banksets.
__device__ __forceinline__ int swz16(int row, int kc) {
    return (row << 7) + ((kc ^ (row & 7)) << 4);
}

// global -> LDS direct copy, 16B per lane. LDS dest = wave-uniform base + lane*16.
typedef __attribute__((address_space(1))) const void gas_void;
typedef __attribute__((address_space(3))) void       las_void;
__device__ __forceinline__ void gload16(const void* g, void* l) {
    __builtin_amdgcn_global_load_lds((gas_void*)g, (las_void*)l, 16, 0, 0);
}

// ---------------------------------------------------------------------------
// Prep: X -> fp16(x/l), XOR-pre-permuted (so linear global_load_lds lands in
// swizzled LDS layout; swizzled ds_read recovers source order — r5-verified),
// plus exact fp32 row norms.
// ---------------------------------------------------------------------------
__global__ __launch_bounds__(256)
void matern52_prep_kernel(const float* __restrict__ X,
                          const float* __restrict__ l,
                          unsigned char* __restrict__ dst,
                          float* __restrict__ sq, int N)
{
    const int t   = threadIdx.x;
    const int kq  = t & 15;
    const int row = blockIdx.x * 16 + (t >> 4);

    float4 lv = *reinterpret_cast<const float4*>(&l[kq * 4]);
    float4 x  = *reinterpret_cast<const float4*>(&X[(size_t)row * N_DIM + kq * 4]);
    const float a0 = x.x / lv.x, a1 = x.y / lv.y, a2 = x.z / lv.z, a3 = x.w / lv.w;

    float s = a0 * a0;
    s = fmaf(a1, a1, s); s = fmaf(a2, a2, s); s = fmaf(a3, a3, s);
    s += __shfl_xor(s, 1);
    s += __shfl_xor(s, 2);
    s += __shfl_xor(s, 4);
    s += __shfl_xor(s, 8);
    if (kq == 0) sq[row] = s;

    f16x4 h = { (_Float16)a0, (_Float16)a1, (_Float16)a2, (_Float16)a3 };
    const int off = (row << 7) + ((((kq >> 1) ^ (row & 7))) << 4) + ((kq & 1) << 3);
    *reinterpret_cast<f16x4*>(dst + off) = h;
}

// ---------------------------------------------------------------------------
// Main: persistent pipelined blocks. 512 thr = 8 waves (4 row x 2 col strips),
// block owns a 256-row A panel (staged once, 32KB LDS) and 4 consecutive
// 128-col B tiles (double-buffered 2x16KB, prefetched 2 ahead). One barrier
// per tile; its implicit vmcnt(0) is covered by the previous tile's epilogue.
// MFMA operand-swapped (reg idx -> out col, lane&15 -> out row; r2-r5
// verified). Regular dwordx4 stores (NT regressed in r6).
// ---------------------------------------------------------------------------
__global__ __launch_bounds__(512, 4)
void matern52_main_kernel(const unsigned char* __restrict__ A16,
                          const unsigned char* __restrict__ B16,
                          const float* __restrict__ sq1,
                          const float* __restrict__ sq2,
                          const float* __restrict__ cc,
                          float* __restrict__ out,
                          int N1, int N2, int njg)
{
    __shared__ __align__(16) unsigned char lds[65536];
    unsigned char* ldsA = lds;              // 32 KB : A panel (256 x 128B)
    // B double-buffer: buffer k at lds + 32768 + k*16384 (computed per iter;
    // a pointer ARRAY init from LDS fails gfx950 codegen - addrspacecast).

    const int t    = threadIdx.x;
    const int bi   = blockIdx.x / njg;      // A panel index (256 rows)
    const int bjg  = blockIdx.x % njg;      // column-tile group (4 tiles)
    const int bj0  = bjg * NTJ;

    const int wbase = (t >> 6) << 10;       // wave-uniform LDS byte base
    const int gb    = t * 16;

    // ---- prologue: stage A (once) + B0 + B1 --------------------------------
    {
        const unsigned char* srcA = A16 + (size_t)bi * (BM * 128);
        #pragma unroll
        for (int i = 0; i < 4; ++i)
            gload16(srcA + i * 8192 + gb, ldsA + i * 8192 + wbase);
        #pragma unroll
        for (int j = 0; j < 2; ++j) {
            const unsigned char* srcB = B16 + (size_t)(bj0 + j) * (BN * 128);
            unsigned char* ldsB = lds + 32768 + j * 16384;
            #pragma unroll
            for (int i = 0; i < 2; ++i)
                gload16(srcB + i * 8192 + gb, ldsB + i * 8192 + wbase);
        }
    }
    __syncthreads();                        // drains vmcnt(0): A, B0, B1 ready

    const int wid  = t >> 6;                // 0..7
    const int lane = t & 63;
    const int wtr  = wid >> 1;              // 0..3 : 64-row strip of the 256
    const int wtc  = wid & 1;               // 0..1 : 64-col strip of the 128
    const int fr   = lane & 15;
    const int kg   = lane >> 4;

    const float c0 = cc[0];
    const float SQ5   = 2.23606797749979f;
    const float FIVE3 = 1.66666666666667f;
    const float NK    = -3.22617785847899f;               // -sqrt5 * log2(e)
    const float l2c2  = 2.885390081777927f * __logf(c0);  // 2*log2(c0)

    const float* sqA = sq1 + bi * BM;

    #pragma unroll
    for (int j = 0; j < NTJ; ++j) {
        unsigned char* ldsB = lds + 32768 + (j & 1) * 16384;

        // ---- fragments + MFMA (per kk: 32 live frag regs + acc 64) --------
        f32x4 acc[4][4] = {};
        #pragma unroll
        for (int kk = 0; kk < 2; ++kk) {
            f16x8 af[4], bg[4];
            #pragma unroll
            for (int m = 0; m < 4; ++m)
                af[m] = *reinterpret_cast<const f16x8*>(
                    ldsA + swz16(wtr * 64 + m * 16 + fr, kk * 4 + kg));
            #pragma unroll
            for (int n = 0; n < 4; ++n)
                bg[n] = *reinterpret_cast<const f16x8*>(
                    ldsB + swz16(wtc * 64 + n * 16 + fr, kk * 4 + kg));
            #pragma unroll
            for (int m = 0; m < 4; ++m)
                #pragma unroll
                for (int n = 0; n < 4; ++n)
                    acc[m][n] = __builtin_amdgcn_mfma_f32_16x16x32_f16(
                        bg[n], af[m], acc[m][n], 0, 0, 0);
        }

        // All waves done reading ldsB(j); implicit vmcnt(0) here waits on the
        // prefetch issued LAST iteration (covered by last epilogue).
        __syncthreads();

        // ---- prefetch B(j+2) into the buffer just freed -------------------
        if (j < NTJ - 2) {
            const unsigned char* srcB = B16 + (size_t)(bj0 + j + 2) * (BN * 128);
            #pragma unroll
            for (int i = 0; i < 2; ++i)
                gload16(srcB + i * 8192 + gb, ldsB + i * 8192 + wbase);
        }

        // ---- epilogue: out = poly(r,d2) * 2^(log2(c^2) - s5*log2e*r) ------
        const int bj = bj0 + j;
        const float* sqB = sq2 + bj * BN + wtc * 64;

        #pragma unroll
        for (int m = 0; m < 4; ++m) {
            const int row_l = wtr * 64 + m * 16 + fr;
            const float sa = sqA[row_l];
            float* rowp = out + ((size_t)(bi * BM) + row_l) * (size_t)N2
                              + (size_t)(bj * BN) + wtc * 64;
            #pragma unroll
            for (int n = 0; n < 4; ++n) {
                const int cb = n * 16 + kg * 4;
                f32x4 sb4 = *reinterpret_cast<const f32x4*>(sqB + cb);
                f32x4 v = acc[m][n];
                f32x4 res;
                #pragma unroll
                for (int q = 0; q < 4; ++q) {
                    float d2 = fmaxf(fmaf(-2.0f, v[q], sa + sb4[q]), 0.0f);
                    float r  = __builtin_amdgcn_sqrtf(d2);
                    float e  = __builtin_amdgcn_exp2f(fmaf(NK, r, l2c2));
                    res[q] = fmaf(FIVE3, d2, fmaf(SQ5, r, 1.0f)) * e;
                }
                *reinterpret_cast<f32x4*>(rowp + cb) = res;
            }
        }
    }
}

// ---------------------------------------------------------------------------
// Fallback (ws too small / odd shapes): self-contained split-bf16 (r3-verified).
// ---------------------------------------------------------------------------
__device__ __forceinline__ ushort_t f2bf(float f) {
    uint_t u = __float_as_uint(f);
    u += 0x7FFFu + ((u >> 16) & 1u);
    return (ushort_t)(u >> 16);
}
__device__ __forceinline__ float bf2f(ushort_t h) {
    return __uint_as_float(((uint_t)h) << 16);
}
typedef short s16x8 __attribute__((ext_vector_type(8)));

__global__ __launch_bounds__(512, 4)
void matern52_fallback_kernel(const float* __restrict__ X1,
                              const float* __restrict__ X2,
                              const float* __restrict__ cc,
                              const float* __restrict__ l,
                              float* __restrict__ out,
                              int N1, int N2)
{
    __shared__ ushort_t Ah[TILE * N_DIM], Al[TILE * N_DIM];
    __shared__ ushort_t Bh[TILE * N_DIM], Bl[TILE * N_DIM];
    __shared__ float sqA[TILE], sqB[TILE];

    const int t  = threadIdx.x;
    const int bi = blockIdx.y, bj = blockIdx.x;
    const int kq   = t & 15;
    const int rsub = t >> 4;

    float4 lv = *reinterpret_cast<const float4*>(&l[kq * 4]);
    const float rlx = 1.f / lv.x, rly = 1.f / lv.y, rlz = 1.f / lv.z, rlw = 1.f / lv.w;
    const float* x1b = X1 + (size_t)(bi * TILE) * N_DIM;
    const float* x2b = X2 + (size_t)(bj * TILE) * N_DIM;

    #define STAGE(Xb, Th, Tl, SQ)                                              \
    {                                                                          \
        _Pragma("unroll")                                                      \
        for (int c = 0; c < 4; ++c) {                                          \
            const int row = c * 32 + rsub;                                     \
            float4 x = *reinterpret_cast<const float4*>(&(Xb)[row * N_DIM + kq * 4]); \
            float a0 = x.x * rlx, a1 = x.y * rly, a2 = x.z * rlz, a3 = x.w * rlw; \
            ushort_t h0 = f2bf(a0), h1 = f2bf(a1), h2 = f2bf(a2), h3 = f2bf(a3); \
            ushort_t e0 = f2bf(a0 - bf2f(h0)), e1 = f2bf(a1 - bf2f(h1));       \
            ushort_t e2 = f2bf(a2 - bf2f(h2)), e3 = f2bf(a3 - bf2f(h3));       \
            const int off = (row << 7) + (((kq >> 1) << 4) ^ ((row & 7) << 4)) + ((kq & 1) << 3); \
            uint2 hv, lvv;                                                     \
            hv.x  = (uint_t)h0 | ((uint_t)h1 << 16);                           \
            hv.y  = (uint_t)h2 | ((uint_t)h3 << 16);                           \
            lvv.x = (uint_t)e0 | ((uint_t)e1 << 16);                           \
            lvv.y = (uint_t)e2 | ((uint_t)e3 << 16);                           \
            *reinterpret_cast<uint2*>((char*)(Th) + off) = hv;                 \
            *reinterpret_cast<uint2*>((char*)(Tl) + off) = lvv;                \
            float s = a0 * a0;                                                 \
            s = fmaf(a1, a1, s); s = fmaf(a2, a2, s); s = fmaf(a3, a3, s);     \
            s += __shfl_xor(s, 1);                                             \
            s += __shfl_xor(s, 2);                                             \
            s += __shfl_xor(s, 4);                                             \
            s += __shfl_xor(s, 8);                                             \
            if (kq == 0) (SQ)[row] = s;                                        \
        }                                                                      \
    }
    STAGE(x1b, Ah, Al, sqA)
    STAGE(x2b, Bh, Bl, sqB)
    #undef STAGE
    __syncthreads();

    const int wid  = t >> 6;
    const int lane = t & 63;
    const int wtr = wid >> 1, wtc = wid & 1;
    const int fr  = lane & 15, kg = lane >> 4;

    f32x4 acc[2][4] = {};
    #pragma unroll
    for (int pass = 0; pass < 3; ++pass) {
        const ushort_t* TA = (pass == 2) ? Al : Ah;
        const ushort_t* TB = (pass == 1) ? Bl : Bh;
        #pragma unroll
        for (int kk = 0; kk < 2; ++kk) {
            s16x8 af[2], bg[4];
            #pragma unroll
            for (int m = 0; m < 2; ++m)
                af[m] = *reinterpret_cast<const s16x8*>(
                    (const char*)TA + swz16(wtr * 32 + m * 16 + fr, kk * 4 + kg));
            #pragma unroll
            for (int n = 0; n < 4; ++n)
                bg[n] = *reinterpret_cast<const s16x8*>(
                    (const char*)TB + swz16(wtc * 64 + n * 16 + fr, kk * 4 + kg));
            #pragma unroll
            for (int m = 0; m < 2; ++m)
                #pragma unroll
                for (int n = 0; n < 4; ++n)
                    acc[m][n] = __builtin_amdgcn_mfma_f32_16x16x32_bf16(
                        bg[n], af[m], acc[m][n], 0, 0, 0);
        }
    }

    const float c0 = cc[0];
    const float SQ5   = 2.23606797749979f;
    const float FIVE3 = 1.66666666666667f;
    const float lnc2  = 2.0f * __logf(c0);

    #pragma unroll
    for (int m = 0; m < 2; ++m) {
        const int row_l = wtr * 32 + m * 16 + fr;
        const float sa = sqA[row_l];
        float* rowp = out + ((size_t)(bi * TILE) + row_l) * (size_t)N2
                          + (size_t)(bj * TILE) + wtc * 64;
        #pragma unroll
        for (int n = 0; n < 4; ++n) {
            const int cb = n * 16 + kg * 4;
            f32x4 sb4 = *reinterpret_cast<const f32x4*>(&sqB[wtc * 64 + cb]);
            f32x4 v = acc[m][n];
            f32x4 res;
            #pragma unroll
            for (int q = 0; q < 4; ++q) {
                float d2 = fmaxf(fmaf(-2.0f, v[q], sa + sb4[q]), 0.0f);
                float r  = sqrtf(d2);
                float e  = __expf(fmaf(-SQ5, r, lnc2));
                res[q] = fmaf(FIVE3, d2, fmaf(SQ5, r, 1.0f)) * e;
            }
            *reinterpret_cast<f32x4*>(rowp + cb) = res;
        }
    }
}

extern "C" void kernel_launch(void* const* d_in, const int* in_sizes, int n_in,
                              void* d_out, int out_size, void* d_ws, size_t ws_size,
                              hipStream_t stream) {
    const float* X1 = (const float*)d_in[0];
    const float* X2 = (const float*)d_in[1];
    const float* c  = (const float*)d_in[2];
    const float* l  = (const float*)d_in[3];
    float* out = (float*)d_out;

    const int N1 = in_sizes[0] / N_DIM;   // 8192
    const int N2 = in_sizes[1] / N_DIM;   // 8192

    const size_t aBytes = (size_t)N1 * 128;
    const size_t bBytes = (size_t)N2 * 128;
    const size_t needWs = aBytes + bBytes + (size_t)(N1 + N2) * sizeof(float);

    const bool shapeOK = (N1 % BM == 0) && (N2 % (BN * NTJ) == 0) &&
                         (N1 % 16 == 0) && (N2 % 16 == 0);

    if (ws_size >= needWs && shapeOK) {
        unsigned char* A16 = (unsigned char*)d_ws;
        unsigned char* B16 = A16 + aBytes;
        float* sq1 = (float*)(B16 + bBytes);
        float* sq2 = sq1 + N1;

        matern52_prep_kernel<<<dim3(N1 / 16), 256, 0, stream>>>(X1, l, A16, sq1, N1);
        matern52_prep_kernel<<<dim3(N2 / 16), 256, 0, stream>>>(X2, l, B16, sq2, N2);

        const int njg  = N2 / (BN * NTJ);            // 16 column-tile groups
        const int nblk = (N1 / BM) * njg;            // 32 * 16 = 512 blocks
        matern52_main_kernel<<<dim3(nblk), 512, 0, stream>>>(
            A16, B16, sq1, sq2, c, out, N1, N2, njg);
    } else {
        dim3 grid(N2 / TILE, N1 / TILE);
        matern52_fallback_kernel<<<grid, 512, 0, stream>>>(X1, X2, c, l, out, N1, N2);
    }
}

// Round 9
// 60.666 us; speedup vs baseline: 1.5102x; 1.0665x over previous
//
#include <hip/hip_runtime.h>
#include <math.h>

#define N_DIM 64
#define TILE  128     // fallback tile
#define BMM   64      // main: rows per block
#define BNN   128     // main: cols per block

typedef unsigned short ushort_t;
typedef unsigned int   uint_t;
typedef _Float16 f16x8 __attribute__((ext_vector_type(8)));
typedef _Float16 f16x4 __attribute__((ext_vector_type(4)));
typedef float    f32x4 __attribute__((ext_vector_type(4)));

// Byte offset of 16B chunk kc (0..7) in row `row` of a [rows x 128B] tile,
// XOR-swizzled (G4): spreads 8 consecutive rows' same-kc chunks over 8 banksets.
__device__ __forceinline__ int swz16(int row, int kc) {
    return (row << 7) + ((kc ^ (row & 7)) << 4);
}

// global -> LDS direct copy, 16B per lane. LDS dest = wave-uniform base + lane*16.
typedef __attribute__((address_space(1))) const void gas_void;
typedef __attribute__((address_space(3))) void       las_void;
__device__ __forceinline__ void gload16(const void* g, void* l) {
    __builtin_amdgcn_global_load_lds((gas_void*)g, (las_void*)l, 16, 0, 0);
}

// ---------------------------------------------------------------------------
// Prep: X -> fp16(x/l), XOR-pre-permuted (row-local permute, tile-size
// independent; linear global_load_lds + swizzled ds_read recovers source
// order — r5-verified), plus exact fp32 row norms.
// ---------------------------------------------------------------------------
__global__ __launch_bounds__(256)
void matern52_prep_kernel(const float* __restrict__ X,
                          const float* __restrict__ l,
                          unsigned char* __restrict__ dst,
                          float* __restrict__ sq, int N)
{
    const int t   = threadIdx.x;
    const int kq  = t & 15;
    const int row = blockIdx.x * 16 + (t >> 4);

    float4 lv = *reinterpret_cast<const float4*>(&l[kq * 4]);
    float4 x  = *reinterpret_cast<const float4*>(&X[(size_t)row * N_DIM + kq * 4]);
    const float a0 = x.x / lv.x, a1 = x.y / lv.y, a2 = x.z / lv.z, a3 = x.w / lv.w;

    float s = a0 * a0;
    s = fmaf(a1, a1, s); s = fmaf(a2, a2, s); s = fmaf(a3, a3, s);
    s += __shfl_xor(s, 1);
    s += __shfl_xor(s, 2);
    s += __shfl_xor(s, 4);
    s += __shfl_xor(s, 8);
    if (kq == 0) sq[row] = s;

    f16x4 h = { (_Float16)a0, (_Float16)a1, (_Float16)a2, (_Float16)a3 };
    const int off = (row << 7) + ((((kq >> 1) ^ (row & 7))) << 4) + ((kq & 1) << 3);
    *reinterpret_cast<f16x4*>(dst + off) = h;
}

// ---------------------------------------------------------------------------
// Main (r5 structure, smaller blocks): 256 thr = 4 waves (2x2), 64x128 tile.
// LDS 24KB + VGPR<=85 (__launch_bounds__(256,6)) -> 6 independent blocks/CU:
// finer phase stagger keeps the store pipe fed (r6/r8 showed coarser units
// regress). Stage via linear global_load_lds of the pre-permuted ws; one
// K=64 fp16 MFMA pass, operand-swapped (reg idx -> out col, lane&15 -> out
// row; r2-r5 verified); exp2 epilogue; regular dwordx4 stores.
// ---------------------------------------------------------------------------
__global__ __launch_bounds__(256, 6)
void matern52_main_kernel(const unsigned char* __restrict__ A16,
                          const unsigned char* __restrict__ B16,
                          const float* __restrict__ sq1,
                          const float* __restrict__ sq2,
                          const float* __restrict__ cc,
                          float* __restrict__ out,
                          int N1, int N2)
{
    __shared__ __align__(16) unsigned char lds[(BMM + BNN) * 128]; // A:8KB | B:16KB

    const int t  = threadIdx.x;
    const int bi = blockIdx.y, bj = blockIdx.x;

    unsigned char* ldsA = lds;
    unsigned char* ldsB = lds + BMM * 128;

    // ---- stage: 6x global_load_lds dwordx4 per thread ----------------------
    {
        const unsigned char* srcA = A16 + (size_t)bi * (BMM * 128);
        const unsigned char* srcB = B16 + (size_t)bj * (BNN * 128);
        const int wbase = (t >> 6) << 10;       // wave-uniform LDS byte base
        const int gb    = t * 16;
        #pragma unroll
        for (int i = 0; i < 2; ++i)
            gload16(srcA + i * 4096 + gb, ldsA + i * 4096 + wbase);
        #pragma unroll
        for (int i = 0; i < 4; ++i)
            gload16(srcB + i * 4096 + gb, ldsB + i * 4096 + wbase);
    }
    __syncthreads();

    // ---- 1-pass fp16 MFMA, K=64 -------------------------------------------
    const int wid  = t >> 6;          // 0..3
    const int lane = t & 63;
    const int wtr  = wid >> 1;        // 0..1 : 32-row strip
    const int wtc  = wid & 1;         // 0..1 : 64-col strip
    const int fr   = lane & 15;
    const int kg   = lane >> 4;

    f32x4 acc[2][4] = {};

    #pragma unroll
    for (int kk = 0; kk < 2; ++kk) {
        f16x8 af[2], bg[4];
        #pragma unroll
        for (int m = 0; m < 2; ++m)
            af[m] = *reinterpret_cast<const f16x8*>(
                ldsA + swz16(wtr * 32 + m * 16 + fr, kk * 4 + kg));
        #pragma unroll
        for (int n = 0; n < 4; ++n)
            bg[n] = *reinterpret_cast<const f16x8*>(
                ldsB + swz16(wtc * 64 + n * 16 + fr, kk * 4 + kg));
        #pragma unroll
        for (int m = 0; m < 2; ++m)
            #pragma unroll
            for (int n = 0; n < 4; ++n)
                acc[m][n] = __builtin_amdgcn_mfma_f32_16x16x32_f16(
                    bg[n], af[m], acc[m][n], 0, 0, 0);
    }

    // ---- epilogue: out = poly(r,d2) * 2^(log2(c^2) - s5*log2e * r) ----------
    const float c0 = cc[0];
    const float SQ5   = 2.23606797749979f;
    const float FIVE3 = 1.66666666666667f;
    const float NK    = -3.22617785847899f;               // -sqrt5 * log2(e)
    const float l2c2  = 2.885390081777927f * __logf(c0);  // 2*log2(c0)

    const float* sqA = sq1 + bi * BMM;
    const float* sqB = sq2 + bj * BNN + wtc * 64;

    #pragma unroll
    for (int m = 0; m < 2; ++m) {
        const int row_l = wtr * 32 + m * 16 + fr;
        const float sa = sqA[row_l];
        float* rowp = out + ((size_t)(bi * BMM) + row_l) * (size_t)N2
                          + (size_t)(bj * BNN) + wtc * 64;
        #pragma unroll
        for (int n = 0; n < 4; ++n) {
            const int cb = n * 16 + kg * 4;
            f32x4 sb4 = *reinterpret_cast<const f32x4*>(sqB + cb);
            f32x4 v = acc[m][n];
            f32x4 res;
            #pragma unroll
            for (int q = 0; q < 4; ++q) {
                float d2 = fmaxf(fmaf(-2.0f, v[q], sa + sb4[q]), 0.0f);
                float r  = __builtin_amdgcn_sqrtf(d2);               // raw v_sqrt_f32
                float e  = __builtin_amdgcn_exp2f(fmaf(NK, r, l2c2)); // raw v_exp_f32
                res[q] = fmaf(FIVE3, d2, fmaf(SQ5, r, 1.0f)) * e;
            }
            *reinterpret_cast<f32x4*>(rowp + cb) = res;
        }
    }
}

// ---------------------------------------------------------------------------
// Fallback (ws too small / odd shapes): self-contained split-bf16 (r3-verified).
// ---------------------------------------------------------------------------
__device__ __forceinline__ ushort_t f2bf(float f) {
    uint_t u = __float_as_uint(f);
    u += 0x7FFFu + ((u >> 16) & 1u);
    return (ushort_t)(u >> 16);
}
__device__ __forceinline__ float bf2f(ushort_t h) {
    return __uint_as_float(((uint_t)h) << 16);
}
typedef short s16x8 __attribute__((ext_vector_type(8)));

__global__ __launch_bounds__(512, 4)
void matern52_fallback_kernel(const float* __restrict__ X1,
                              const float* __restrict__ X2,
                              const float* __restrict__ cc,
                              const float* __restrict__ l,
                              float* __restrict__ out,
                              int N1, int N2)
{
    __shared__ ushort_t Ah[TILE * N_DIM], Al[TILE * N_DIM];
    __shared__ ushort_t Bh[TILE * N_DIM], Bl[TILE * N_DIM];
    __shared__ float sqA[TILE], sqB[TILE];

    const int t  = threadIdx.x;
    const int bi = blockIdx.y, bj = blockIdx.x;
    const int kq   = t & 15;
    const int rsub = t >> 4;

    float4 lv = *reinterpret_cast<const float4*>(&l[kq * 4]);
    const float rlx = 1.f / lv.x, rly = 1.f / lv.y, rlz = 1.f / lv.z, rlw = 1.f / lv.w;
    const float* x1b = X1 + (size_t)(bi * TILE) * N_DIM;
    const float* x2b = X2 + (size_t)(bj * TILE) * N_DIM;

    #define STAGE(Xb, Th, Tl, SQ)                                              \
    {                                                                          \
        _Pragma("unroll")                                                      \
        for (int c = 0; c < 4; ++c) {                                          \
            const int row = c * 32 + rsub;                                     \
            float4 x = *reinterpret_cast<const float4*>(&(Xb)[row * N_DIM + kq * 4]); \
            float a0 = x.x * rlx, a1 = x.y * rly, a2 = x.z * rlz, a3 = x.w * rlw; \
            ushort_t h0 = f2bf(a0), h1 = f2bf(a1), h2 = f2bf(a2), h3 = f2bf(a3); \
            ushort_t e0 = f2bf(a0 - bf2f(h0)), e1 = f2bf(a1 - bf2f(h1));       \
            ushort_t e2 = f2bf(a2 - bf2f(h2)), e3 = f2bf(a3 - bf2f(h3));       \
            const int off = (row << 7) + (((kq >> 1) << 4) ^ ((row & 7) << 4)) + ((kq & 1) << 3); \
            uint2 hv, lvv;                                                     \
            hv.x  = (uint_t)h0 | ((uint_t)h1 << 16);                           \
            hv.y  = (uint_t)h2 | ((uint_t)h3 << 16);                           \
            lvv.x = (uint_t)e0 | ((uint_t)e1 << 16);                           \
            lvv.y = (uint_t)e2 | ((uint_t)e3 << 16);                           \
            *reinterpret_cast<uint2*>((char*)(Th) + off) = hv;                 \
            *reinterpret_cast<uint2*>((char*)(Tl) + off) = lvv;                \
            float s = a0 * a0;                                                 \
            s = fmaf(a1, a1, s); s = fmaf(a2, a2, s); s = fmaf(a3, a3, s);     \
            s += __shfl_xor(s, 1);                                             \
            s += __shfl_xor(s, 2);                                             \
            s += __shfl_xor(s, 4);                                             \
            s += __shfl_xor(s, 8);                                             \
            if (kq == 0) (SQ)[row] = s;                                        \
        }                                                                      \
    }
    STAGE(x1b, Ah, Al, sqA)
    STAGE(x2b, Bh, Bl, sqB)
    #undef STAGE
    __syncthreads();

    const int wid  = t >> 6;
    const int lane = t & 63;
    const int wtr = wid >> 1, wtc = wid & 1;
    const int fr  = lane & 15, kg = lane >> 4;

    f32x4 acc[2][4] = {};
    #pragma unroll
    for (int pass = 0; pass < 3; ++pass) {
        const ushort_t* TA = (pass == 2) ? Al : Ah;
        const ushort_t* TB = (pass == 1) ? Bl : Bh;
        #pragma unroll
        for (int kk = 0; kk < 2; ++kk) {
            s16x8 af[2], bg[4];
            #pragma unroll
            for (int m = 0; m < 2; ++m)
                af[m] = *reinterpret_cast<const s16x8*>(
                    (const char*)TA + swz16(wtr * 32 + m * 16 + fr, kk * 4 + kg));
            #pragma unroll
            for (int n = 0; n < 4; ++n)
                bg[n] = *reinterpret_cast<const s16x8*>(
                    (const char*)TB + swz16(wtc * 64 + n * 16 + fr, kk * 4 + kg));
            #pragma unroll
            for (int m = 0; m < 2; ++m)
                #pragma unroll
                for (int n = 0; n < 4; ++n)
                    acc[m][n] = __builtin_amdgcn_mfma_f32_16x16x32_bf16(
                        bg[n], af[m], acc[m][n], 0, 0, 0);
        }
    }

    const float c0 = cc[0];
    const float SQ5   = 2.23606797749979f;
    const float FIVE3 = 1.66666666666667f;
    const float lnc2  = 2.0f * __logf(c0);

    #pragma unroll
    for (int m = 0; m < 2; ++m) {
        const int row_l = wtr * 32 + m * 16 + fr;
        const float sa = sqA[row_l];
        float* rowp = out + ((size_t)(bi * TILE) + row_l) * (size_t)N2
                          + (size_t)(bj * TILE) + wtc * 64;
        #pragma unroll
        for (int n = 0; n < 4; ++n) {
            const int cb = n * 16 + kg * 4;
            f32x4 sb4 = *reinterpret_cast<const f32x4*>(&sqB[wtc * 64 + cb]);
            f32x4 v = acc[m][n];
            f32x4 res;
            #pragma unroll
            for (int q = 0; q < 4; ++q) {
                float d2 = fmaxf(fmaf(-2.0f, v[q], sa + sb4[q]), 0.0f);
                float r  = sqrtf(d2);
                float e  = __expf(fmaf(-SQ5, r, lnc2));
                res[q] = fmaf(FIVE3, d2, fmaf(SQ5, r, 1.0f)) * e;
            }
            *reinterpret_cast<f32x4*>(rowp + cb) = res;
        }
    }
}

extern "C" void kernel_launch(void* const* d_in, const int* in_sizes, int n_in,
                              void* d_out, int out_size, void* d_ws, size_t ws_size,
                              hipStream_t stream) {
    const float* X1 = (const float*)d_in[0];
    const float* X2 = (const float*)d_in[1];
    const float* c  = (const float*)d_in[2];
    const float* l  = (const float*)d_in[3];
    float* out = (float*)d_out;

    const int N1 = in_sizes[0] / N_DIM;   // 8192
    const int N2 = in_sizes[1] / N_DIM;   // 8192

    const size_t aBytes = (size_t)N1 * 128;
    const size_t bBytes = (size_t)N2 * 128;
    const size_t needWs = aBytes + bBytes + (size_t)(N1 + N2) * sizeof(float);

    const bool shapeOK = (N1 % BMM == 0) && (N2 % BNN == 0) &&
                         (N1 % 16 == 0) && (N2 % 16 == 0);

    if (ws_size >= needWs && shapeOK) {
        unsigned char* A16 = (unsigned char*)d_ws;
        unsigned char* B16 = A16 + aBytes;
        float* sq1 = (float*)(B16 + bBytes);
        float* sq2 = sq1 + N1;

        matern52_prep_kernel<<<dim3(N1 / 16), 256, 0, stream>>>(X1, l, A16, sq1, N1);
        matern52_prep_kernel<<<dim3(N2 / 16), 256, 0, stream>>>(X2, l, B16, sq2, N2);

        dim3 grid(N2 / BNN, N1 / BMM);    // 64 x 128 = 8192 blocks
        matern52_main_kernel<<<grid, 256, 0, stream>>>(
            A16, B16, sq1, sq2, c, out, N1, N2);
    } else {
        dim3 grid(N2 / TILE, N1 / TILE);
        matern52_fallback_kernel<<<grid, 512, 0, stream>>>(X1, X2, c, l, out, N1, N2);
    }
}

// Round 10
// 58.935 us; speedup vs baseline: 1.5546x; 1.0294x over previous
//
#include <hip/hip_runtime.h>
#include <math.h>

#define N_DIM 64
#define TILE  128

typedef unsigned short ushort_t;
typedef unsigned int   uint_t;
typedef _Float16 f16x8 __attribute__((ext_vector_type(8)));
typedef _Float16 f16x4 __attribute__((ext_vector_type(4)));
typedef float    f32x4 __attribute__((ext_vector_type(4)));

// Byte offset of 16B chunk kc (0..7) in row `row` of a [rows x 128B] tile,
// XOR-swizzled (G4): spreads 8 consecutive rows' same-kc chunks over 8 banksets.
__device__ __forceinline__ int swz16(int row, int kc) {
    return (row << 7) + ((kc ^ (row & 7)) << 4);
}

// global -> LDS direct copy, 16B per lane. LDS dest = wave-uniform base + lane*16.
typedef __attribute__((address_space(1))) const void gas_void;
typedef __attribute__((address_space(3))) void       las_void;
__device__ __forceinline__ void gload16(const void* g, void* l) {
    __builtin_amdgcn_global_load_lds((gas_void*)g, (las_void*)l, 16, 0, 0);
}

// ---------------------------------------------------------------------------
// Prep (X1 and X2 in ONE dispatch): X -> fp16(x/l), XOR-pre-permuted
// (linear global_load_lds + swizzled ds_read recovers source order —
// r5-verified), plus exact fp32 row norms. Blocks cover 16 rows each;
// N1 % 16 == 0 so each block is entirely within X1 or X2 (uniform branch).
// ---------------------------------------------------------------------------
__global__ __launch_bounds__(256)
void matern52_prep_kernel(const float* __restrict__ X1,
                          const float* __restrict__ X2,
                          const float* __restrict__ l,
                          unsigned char* __restrict__ dstA,
                          unsigned char* __restrict__ dstB,
                          float* __restrict__ sq1,
                          float* __restrict__ sq2,
                          int N1)
{
    const int t  = threadIdx.x;
    const int kq = t & 15;
    int row = blockIdx.x * 16 + (t >> 4);

    const float* __restrict__ X;
    unsigned char* __restrict__ dst;
    float* __restrict__ sq;
    if (row < N1) { X = X1; dst = dstA; sq = sq1; }
    else          { X = X2; dst = dstB; sq = sq2; row -= N1; }

    float4 lv = *reinterpret_cast<const float4*>(&l[kq * 4]);
    float4 x  = *reinterpret_cast<const float4*>(&X[(size_t)row * N_DIM + kq * 4]);
    const float a0 = x.x / lv.x, a1 = x.y / lv.y, a2 = x.z / lv.z, a3 = x.w / lv.w;

    float s = a0 * a0;
    s = fmaf(a1, a1, s); s = fmaf(a2, a2, s); s = fmaf(a3, a3, s);
    s += __shfl_xor(s, 1);
    s += __shfl_xor(s, 2);
    s += __shfl_xor(s, 4);
    s += __shfl_xor(s, 8);
    if (kq == 0) sq[row] = s;

    f16x4 h = { (_Float16)a0, (_Float16)a1, (_Float16)a2, (_Float16)a3 };
    const int off = (row << 7) + ((((kq >> 1) ^ (row & 7))) << 4) + ((kq & 1) << 3);
    *reinterpret_cast<f16x4*>(dst + off) = h;
}

// ---------------------------------------------------------------------------
// Main: r5-verified structure (256 thr = 4 waves 2x2, 128x128 tile, 32KB LDS,
// gload_lds staging, 1-pass K=64 fp16 MFMA operand-swapped, exp2 epilogue,
// dwordx4 stores) + ONE change: chunked XCD swizzle (T1). Linear grid;
// newid = (orig&7)*(nblk/8) + orig/8 gives each XCD a contiguous 1/8 of the
// tile space -> each XCD's L2 emits one dense 32MB write stream (rows-band),
// restoring DRAM page locality that round-robin dispatch destroys.
// ---------------------------------------------------------------------------
__global__ __launch_bounds__(256, 4)
void matern52_main_kernel(const unsigned char* __restrict__ A16,
                          const unsigned char* __restrict__ B16,
                          const float* __restrict__ sq1,
                          const float* __restrict__ sq2,
                          const float* __restrict__ cc,
                          float* __restrict__ out,
                          int N1, int N2, int nbx, int chunk)
{
    __shared__ __align__(16) unsigned char lds[2 * TILE * N_DIM * 2]; // A:16KB | B:16KB

    const int t = threadIdx.x;

    // chunked XCD swizzle (bijective: nblk % 8 == 0 guaranteed by caller)
    const int orig  = blockIdx.x;
    const int newid = (orig & 7) * chunk + (orig >> 3);
    const int bi    = newid / nbx;
    const int bj    = newid % nbx;

    unsigned char* ldsA = lds;
    unsigned char* ldsB = lds + TILE * N_DIM * 2;

    // ---- stage: 8x global_load_lds dwordx4 per thread ----------------------
    {
        const unsigned char* srcA = A16 + (size_t)bi * (TILE * 128);
        const unsigned char* srcB = B16 + (size_t)bj * (TILE * 128);
        const int wbase = (t >> 6) << 10;       // wave-uniform LDS byte base
        const int gb    = t * 16;
        #pragma unroll
        for (int i = 0; i < 4; ++i) {
            gload16(srcA + i * 4096 + gb, ldsA + i * 4096 + wbase);
            gload16(srcB + i * 4096 + gb, ldsB + i * 4096 + wbase);
        }
    }
    __syncthreads();

    // ---- 1-pass fp16 MFMA, K=64 -------------------------------------------
    const int wid  = t >> 6;          // 0..3
    const int lane = t & 63;
    const int wtr  = wid >> 1;        // 0..1 : 64-row strip
    const int wtc  = wid & 1;         // 0..1 : 64-col strip
    const int fr   = lane & 15;
    const int kg   = lane >> 4;

    f32x4 acc[4][4] = {};

    #pragma unroll
    for (int kk = 0; kk < 2; ++kk) {
        f16x8 af[4], bg[4];
        #pragma unroll
        for (int m = 0; m < 4; ++m)
            af[m] = *reinterpret_cast<const f16x8*>(
                ldsA + swz16(wtr * 64 + m * 16 + fr, kk * 4 + kg));
        #pragma unroll
        for (int n = 0; n < 4; ++n)
            bg[n] = *reinterpret_cast<const f16x8*>(
                ldsB + swz16(wtc * 64 + n * 16 + fr, kk * 4 + kg));
        // swapped operands (r2-r5 verified): lane&15 -> out row, reg -> out col
        #pragma unroll
        for (int m = 0; m < 4; ++m)
            #pragma unroll
            for (int n = 0; n < 4; ++n)
                acc[m][n] = __builtin_amdgcn_mfma_f32_16x16x32_f16(
                    bg[n], af[m], acc[m][n], 0, 0, 0);
    }

    // ---- epilogue: out = poly(r,d2) * 2^(log2(c^2) - s5*log2e * r) ----------
    const float c0 = cc[0];
    const float SQ5   = 2.23606797749979f;
    const float FIVE3 = 1.66666666666667f;
    const float NK    = -3.22617785847899f;               // -sqrt5 * log2(e)
    const float l2c2  = 2.885390081777927f * __logf(c0);  // 2*log2(c0)

    const float* sqA = sq1 + bi * TILE;
    const float* sqB = sq2 + bj * TILE + wtc * 64;

    #pragma unroll
    for (int m = 0; m < 4; ++m) {
        const int row_l = wtr * 64 + m * 16 + fr;
        const float sa = sqA[row_l];
        float* rowp = out + ((size_t)(bi * TILE) + row_l) * (size_t)N2
                          + (size_t)(bj * TILE) + wtc * 64;
        #pragma unroll
        for (int n = 0; n < 4; ++n) {
            const int cb = n * 16 + kg * 4;
            f32x4 sb4 = *reinterpret_cast<const f32x4*>(sqB + cb);
            f32x4 v = acc[m][n];
            f32x4 res;
            #pragma unroll
            for (int q = 0; q < 4; ++q) {
                float d2 = fmaxf(fmaf(-2.0f, v[q], sa + sb4[q]), 0.0f);
                float r  = __builtin_amdgcn_sqrtf(d2);               // raw v_sqrt_f32
                float e  = __builtin_amdgcn_exp2f(fmaf(NK, r, l2c2)); // raw v_exp_f32
                res[q] = fmaf(FIVE3, d2, fmaf(SQ5, r, 1.0f)) * e;
            }
            *reinterpret_cast<f32x4*>(rowp + cb) = res;
        }
    }
}

// ---------------------------------------------------------------------------
// Fallback (ws too small / odd shapes): self-contained split-bf16 (r3-verified).
// ---------------------------------------------------------------------------
__device__ __forceinline__ ushort_t f2bf(float f) {
    uint_t u = __float_as_uint(f);
    u += 0x7FFFu + ((u >> 16) & 1u);
    return (ushort_t)(u >> 16);
}
__device__ __forceinline__ float bf2f(ushort_t h) {
    return __uint_as_float(((uint_t)h) << 16);
}
typedef short s16x8 __attribute__((ext_vector_type(8)));

__global__ __launch_bounds__(512, 4)
void matern52_fallback_kernel(const float* __restrict__ X1,
                              const float* __restrict__ X2,
                              const float* __restrict__ cc,
                              const float* __restrict__ l,
                              float* __restrict__ out,
                              int N1, int N2)
{
    __shared__ ushort_t Ah[TILE * N_DIM], Al[TILE * N_DIM];
    __shared__ ushort_t Bh[TILE * N_DIM], Bl[TILE * N_DIM];
    __shared__ float sqA[TILE], sqB[TILE];

    const int t  = threadIdx.x;
    const int bi = blockIdx.y, bj = blockIdx.x;
    const int kq   = t & 15;
    const int rsub = t >> 4;

    float4 lv = *reinterpret_cast<const float4*>(&l[kq * 4]);
    const float rlx = 1.f / lv.x, rly = 1.f / lv.y, rlz = 1.f / lv.z, rlw = 1.f / lv.w;
    const float* x1b = X1 + (size_t)(bi * TILE) * N_DIM;
    const float* x2b = X2 + (size_t)(bj * TILE) * N_DIM;

    #define STAGE(Xb, Th, Tl, SQ)                                              \
    {                                                                          \
        _Pragma("unroll")                                                      \
        for (int c = 0; c < 4; ++c) {                                          \
            const int row = c * 32 + rsub;                                     \
            float4 x = *reinterpret_cast<const float4*>(&(Xb)[row * N_DIM + kq * 4]); \
            float a0 = x.x * rlx, a1 = x.y * rly, a2 = x.z * rlz, a3 = x.w * rlw; \
            ushort_t h0 = f2bf(a0), h1 = f2bf(a1), h2 = f2bf(a2), h3 = f2bf(a3); \
            ushort_t e0 = f2bf(a0 - bf2f(h0)), e1 = f2bf(a1 - bf2f(h1));       \
            ushort_t e2 = f2bf(a2 - bf2f(h2)), e3 = f2bf(a3 - bf2f(h3));       \
            const int off = (row << 7) + (((kq >> 1) << 4) ^ ((row & 7) << 4)) + ((kq & 1) << 3); \
            uint2 hv, lvv;                                                     \
            hv.x  = (uint_t)h0 | ((uint_t)h1 << 16);                           \
            hv.y  = (uint_t)h2 | ((uint_t)h3 << 16);                           \
            lvv.x = (uint_t)e0 | ((uint_t)e1 << 16);                           \
            lvv.y = (uint_t)e2 | ((uint_t)e3 << 16);                           \
            *reinterpret_cast<uint2*>((char*)(Th) + off) = hv;                 \
            *reinterpret_cast<uint2*>((char*)(Tl) + off) = lvv;                \
            float s = a0 * a0;                                                 \
            s = fmaf(a1, a1, s); s = fmaf(a2, a2, s); s = fmaf(a3, a3, s);     \
            s += __shfl_xor(s, 1);                                             \
            s += __shfl_xor(s, 2);                                             \
            s += __shfl_xor(s, 4);                                             \
            s += __shfl_xor(s, 8);                                             \
            if (kq == 0) (SQ)[row] = s;                                        \
        }                                                                      \
    }
    STAGE(x1b, Ah, Al, sqA)
    STAGE(x2b, Bh, Bl, sqB)
    #undef STAGE
    __syncthreads();

    const int wid  = t >> 6;
    const int lane = t & 63;
    const int wtr = wid >> 1, wtc = wid & 1;
    const int fr  = lane & 15, kg = lane >> 4;

    f32x4 acc[2][4] = {};
    #pragma unroll
    for (int pass = 0; pass < 3; ++pass) {
        const ushort_t* TA = (pass == 2) ? Al : Ah;
        const ushort_t* TB = (pass == 1) ? Bl : Bh;
        #pragma unroll
        for (int kk = 0; kk < 2; ++kk) {
            s16x8 af[2], bg[4];
            #pragma unroll
            for (int m = 0; m < 2; ++m)
                af[m] = *reinterpret_cast<const s16x8*>(
                    (const char*)TA + swz16(wtr * 32 + m * 16 + fr, kk * 4 + kg));
            #pragma unroll
            for (int n = 0; n < 4; ++n)
                bg[n] = *reinterpret_cast<const s16x8*>(
                    (const char*)TB + swz16(wtc * 64 + n * 16 + fr, kk * 4 + kg));
            #pragma unroll
            for (int m = 0; m < 2; ++m)
                #pragma unroll
                for (int n = 0; n < 4; ++n)
                    acc[m][n] = __builtin_amdgcn_mfma_f32_16x16x32_bf16(
                        bg[n], af[m], acc[m][n], 0, 0, 0);
        }
    }

    const float c0 = cc[0];
    const float SQ5   = 2.23606797749979f;
    const float FIVE3 = 1.66666666666667f;
    const float lnc2  = 2.0f * __logf(c0);

    #pragma unroll
    for (int m = 0; m < 2; ++m) {
        const int row_l = wtr * 32 + m * 16 + fr;
        const float sa = sqA[row_l];
        float* rowp = out + ((size_t)(bi * TILE) + row_l) * (size_t)N2
                          + (size_t)(bj * TILE) + wtc * 64;
        #pragma unroll
        for (int n = 0; n < 4; ++n) {
            const int cb = n * 16 + kg * 4;
            f32x4 sb4 = *reinterpret_cast<const f32x4*>(&sqB[wtc * 64 + cb]);
            f32x4 v = acc[m][n];
            f32x4 res;
            #pragma unroll
            for (int q = 0; q < 4; ++q) {
                float d2 = fmaxf(fmaf(-2.0f, v[q], sa + sb4[q]), 0.0f);
                float r  = sqrtf(d2);
                float e  = __expf(fmaf(-SQ5, r, lnc2));
                res[q] = fmaf(FIVE3, d2, fmaf(SQ5, r, 1.0f)) * e;
            }
            *reinterpret_cast<f32x4*>(rowp + cb) = res;
        }
    }
}

extern "C" void kernel_launch(void* const* d_in, const int* in_sizes, int n_in,
                              void* d_out, int out_size, void* d_ws, size_t ws_size,
                              hipStream_t stream) {
    const float* X1 = (const float*)d_in[0];
    const float* X2 = (const float*)d_in[1];
    const float* c  = (const float*)d_in[2];
    const float* l  = (const float*)d_in[3];
    float* out = (float*)d_out;

    const int N1 = in_sizes[0] / N_DIM;   // 8192
    const int N2 = in_sizes[1] / N_DIM;   // 8192

    const size_t aBytes = (size_t)N1 * 128;
    const size_t bBytes = (size_t)N2 * 128;
    const size_t needWs = aBytes + bBytes + (size_t)(N1 + N2) * sizeof(float);

    const int nby  = N1 / TILE;           // 64
    const int nbx  = N2 / TILE;           // 64
    const int nblk = nby * nbx;           // 4096

    const bool shapeOK = (N1 % TILE == 0) && (N2 % TILE == 0) &&
                         (N1 % 16 == 0) && (nblk % 8 == 0);

    if (ws_size >= needWs && shapeOK) {
        unsigned char* A16 = (unsigned char*)d_ws;
        unsigned char* B16 = A16 + aBytes;
        float* sq1 = (float*)(B16 + bBytes);
        float* sq2 = sq1 + N1;

        matern52_prep_kernel<<<dim3((N1 + N2) / 16), 256, 0, stream>>>(
            X1, X2, l, A16, B16, sq1, sq2, N1);

        matern52_main_kernel<<<dim3(nblk), 256, 0, stream>>>(
            A16, B16, sq1, sq2, c, out, N1, N2, nbx, nblk / 8);
    } else {
        dim3 grid(N2 / TILE, N1 / TILE);
        matern52_fallback_kernel<<<grid, 512, 0, stream>>>(X1, X2, c, l, out, N1, N2);
    }
}

// Round 11
// 58.382 us; speedup vs baseline: 1.5693x; 1.0095x over previous
//
#include <hip/hip_runtime.h>
#include <math.h>

#define N_DIM 64
#define TILE  128

typedef unsigned short ushort_t;
typedef unsigned int   uint_t;
typedef _Float16 f16x8 __attribute__((ext_vector_type(8)));
typedef _Float16 f16x4 __attribute__((ext_vector_type(4)));
typedef float    f32x4 __attribute__((ext_vector_type(4)));

// Byte offset of 16B chunk kc (0..7) in row `row` of a [rows x 128B] tile,
// XOR-swizzled (G4): spreads 8 consecutive rows' same-kc chunks over 8 banksets.
__device__ __forceinline__ int swz16(int row, int kc) {
    return (row << 7) + ((kc ^ (row & 7)) << 4);
}

// global -> LDS direct copy, 16B per lane. LDS dest = wave-uniform base + lane*16.
typedef __attribute__((address_space(1))) const void gas_void;
typedef __attribute__((address_space(3))) void       las_void;
__device__ __forceinline__ void gload16(const void* g, void* l) {
    __builtin_amdgcn_global_load_lds((gas_void*)g, (las_void*)l, 16, 0, 0);
}

// ---------------------------------------------------------------------------
// Prep (X1 and X2 in ONE dispatch): X -> fp16(x/l), XOR-pre-permuted
// (linear global_load_lds + swizzled ds_read recovers source order —
// r5-verified), plus exact fp32 row norms.
// ---------------------------------------------------------------------------
__global__ __launch_bounds__(256)
void matern52_prep_kernel(const float* __restrict__ X1,
                          const float* __restrict__ X2,
                          const float* __restrict__ l,
                          unsigned char* __restrict__ dstA,
                          unsigned char* __restrict__ dstB,
                          float* __restrict__ sq1,
                          float* __restrict__ sq2,
                          int N1)
{
    const int t  = threadIdx.x;
    const int kq = t & 15;
    int row = blockIdx.x * 16 + (t >> 4);

    const float* __restrict__ X;
    unsigned char* __restrict__ dst;
    float* __restrict__ sq;
    if (row < N1) { X = X1; dst = dstA; sq = sq1; }
    else          { X = X2; dst = dstB; sq = sq2; row -= N1; }

    float4 lv = *reinterpret_cast<const float4*>(&l[kq * 4]);
    float4 x  = *reinterpret_cast<const float4*>(&X[(size_t)row * N_DIM + kq * 4]);
    const float a0 = x.x / lv.x, a1 = x.y / lv.y, a2 = x.z / lv.z, a3 = x.w / lv.w;

    float s = a0 * a0;
    s = fmaf(a1, a1, s); s = fmaf(a2, a2, s); s = fmaf(a3, a3, s);
    s += __shfl_xor(s, 1);
    s += __shfl_xor(s, 2);
    s += __shfl_xor(s, 4);
    s += __shfl_xor(s, 8);
    if (kq == 0) sq[row] = s;

    f16x4 h = { (_Float16)a0, (_Float16)a1, (_Float16)a2, (_Float16)a3 };
    const int off = (row << 7) + ((((kq >> 1) ^ (row & 7))) << 4) + ((kq & 1) << 3);
    *reinterpret_cast<f16x4*>(dst + off) = h;
}

// ---------------------------------------------------------------------------
// Main: r10 structure (256 thr = 4 waves 2x2, 128x128 tile, 32KB LDS,
// gload_lds staging, 1-pass K=64 fp16 MFMA operand-swapped, exp2 epilogue,
// chunked XCD swizzle) + ONE change: LDS-BOUNCE TRANSPOSED STORES.
// The MFMA C-layout (row=lane&15, colchunk=lane>>4) makes a direct dwordx4
// store write 16 scattered 64B segments/inst -> 2x write transactions/byte
// (store path is txn-rate-limited ~4/cyc/XCD; fill=128B lines hits 7TB/s,
// we cap at 4.6). Bounce each 16x64 f32 result subtile through wave-private
// LDS scratch (XOR-swizzled, balanced b128s), read back row-contiguous, so
// every global store inst = 4 rows x 256B contiguous = full 128B lines.
// Intra-wave ds write->read is HW-ordered (in-order DS pipe); wave_barrier
// pins compiler ordering. Scratch reuses staging LDS after one barrier.
// ---------------------------------------------------------------------------
__global__ __launch_bounds__(256, 4)
void matern52_main_kernel(const unsigned char* __restrict__ A16,
                          const unsigned char* __restrict__ B16,
                          const float* __restrict__ sq1,
                          const float* __restrict__ sq2,
                          const float* __restrict__ cc,
                          float* __restrict__ out,
                          int N1, int N2, int nbx, int chunk)
{
    __shared__ __align__(16) unsigned char lds[2 * TILE * N_DIM * 2]; // 32 KB

    const int t = threadIdx.x;

    // chunked XCD swizzle (bijective: nblk % 8 == 0 guaranteed by caller)
    const int orig  = blockIdx.x;
    const int newid = (orig & 7) * chunk + (orig >> 3);
    const int bi    = newid / nbx;
    const int bj    = newid % nbx;

    unsigned char* ldsA = lds;
    unsigned char* ldsB = lds + TILE * N_DIM * 2;

    // ---- stage: 8x global_load_lds dwordx4 per thread ----------------------
    {
        const unsigned char* srcA = A16 + (size_t)bi * (TILE * 128);
        const unsigned char* srcB = B16 + (size_t)bj * (TILE * 128);
        const int wbase = (t >> 6) << 10;       // wave-uniform LDS byte base
        const int gb    = t * 16;
        #pragma unroll
        for (int i = 0; i < 4; ++i) {
            gload16(srcA + i * 4096 + gb, ldsA + i * 4096 + wbase);
            gload16(srcB + i * 4096 + gb, ldsB + i * 4096 + wbase);
        }
    }
    __syncthreads();

    // ---- 1-pass fp16 MFMA, K=64 -------------------------------------------
    const int wid  = t >> 6;          // 0..3
    const int lane = t & 63;
    const int wtr  = wid >> 1;        // 0..1 : 64-row strip
    const int wtc  = wid & 1;         // 0..1 : 64-col strip
    const int fr   = lane & 15;
    const int kg   = lane >> 4;

    f32x4 acc[4][4] = {};

    #pragma unroll
    for (int kk = 0; kk < 2; ++kk) {
        f16x8 af[4], bg[4];
        #pragma unroll
        for (int m = 0; m < 4; ++m)
            af[m] = *reinterpret_cast<const f16x8*>(
                ldsA + swz16(wtr * 64 + m * 16 + fr, kk * 4 + kg));
        #pragma unroll
        for (int n = 0; n < 4; ++n)
            bg[n] = *reinterpret_cast<const f16x8*>(
                ldsB + swz16(wtc * 64 + n * 16 + fr, kk * 4 + kg));
        // swapped operands (r2-r5 verified): lane&15 -> out row, reg -> out col
        #pragma unroll
        for (int m = 0; m < 4; ++m)
            #pragma unroll
            for (int n = 0; n < 4; ++n)
                acc[m][n] = __builtin_amdgcn_mfma_f32_16x16x32_f16(
                    bg[n], af[m], acc[m][n], 0, 0, 0);
    }

    // all waves done with fragment ds_reads; staging LDS reusable as scratch
    __syncthreads();

    // ---- epilogue with LDS-bounce transposed stores ------------------------
    const float c0 = cc[0];
    const float SQ5   = 2.23606797749979f;
    const float FIVE3 = 1.66666666666667f;
    const float NK    = -3.22617785847899f;               // -sqrt5 * log2(e)
    const float l2c2  = 2.885390081777927f * __logf(c0);  // 2*log2(c0)

    const float* sqA = sq1 + bi * TILE;
    const float* sqB = sq2 + bj * TILE + wtc * 64;

    unsigned char* scr = lds + (wid << 12);   // 4 KB wave-private scratch

    f32x4 sb4[4];
    #pragma unroll
    for (int n = 0; n < 4; ++n)
        sb4[n] = *reinterpret_cast<const f32x4*>(sqB + n * 16 + kg * 4);

    const int r_off = lane >> 4;              // 0..3 : row sub-index on readback
    const int c16   = lane & 15;              // 16B column chunk on readback

    #pragma unroll
    for (int m = 0; m < 4; ++m) {
        const float sa = sqA[wtr * 64 + m * 16 + fr];

        // compute + scatter into scratch [16 rows][64 cols] f32, XOR-swizzled
        #pragma unroll
        for (int n = 0; n < 4; ++n) {
            f32x4 v = acc[m][n];
            f32x4 res;
            #pragma unroll
            for (int q = 0; q < 4; ++q) {
                float d2 = fmaxf(fmaf(-2.0f, v[q], sa + sb4[n][q]), 0.0f);
                float r  = __builtin_amdgcn_sqrtf(d2);               // raw v_sqrt_f32
                float e  = __builtin_amdgcn_exp2f(fmaf(NK, r, l2c2)); // raw v_exp_f32
                res[q] = fmaf(FIVE3, d2, fmaf(SQ5, r, 1.0f)) * e;
            }
            const int boff = (fr << 8) + ((((n << 6) + (kg << 4))) ^ ((fr & 7) << 4));
            *reinterpret_cast<f32x4*>(scr + boff) = res;
        }

        __builtin_amdgcn_wave_barrier();      // pin write->read order (HW DS in-order)

        // read back row-contiguous, store 4 rows x 256B contiguous per inst
        #pragma unroll
        for (int i = 0; i < 4; ++i) {
            const int rr = i * 4 + r_off;     // 0..15
            const int rb = (rr << 8) + ((c16 << 4) ^ ((rr & 7) << 4));
            f32x4 val = *reinterpret_cast<const f32x4*>(scr + rb);
            const int grow = wtr * 64 + m * 16 + rr;
            float* p = out + ((size_t)(bi * TILE) + grow) * (size_t)N2
                           + (size_t)(bj * TILE) + wtc * 64 + c16 * 4;
            *reinterpret_cast<f32x4*>(p) = val;
        }

        __builtin_amdgcn_wave_barrier();      // reads of m before writes of m+1
    }
}

// ---------------------------------------------------------------------------
// Fallback (ws too small / odd shapes): self-contained split-bf16 (r3-verified).
// ---------------------------------------------------------------------------
__device__ __forceinline__ ushort_t f2bf(float f) {
    uint_t u = __float_as_uint(f);
    u += 0x7FFFu + ((u >> 16) & 1u);
    return (ushort_t)(u >> 16);
}
__device__ __forceinline__ float bf2f(ushort_t h) {
    return __uint_as_float(((uint_t)h) << 16);
}
typedef short s16x8 __attribute__((ext_vector_type(8)));

__global__ __launch_bounds__(512, 4)
void matern52_fallback_kernel(const float* __restrict__ X1,
                              const float* __restrict__ X2,
                              const float* __restrict__ cc,
                              const float* __restrict__ l,
                              float* __restrict__ out,
                              int N1, int N2)
{
    __shared__ ushort_t Ah[TILE * N_DIM], Al[TILE * N_DIM];
    __shared__ ushort_t Bh[TILE * N_DIM], Bl[TILE * N_DIM];
    __shared__ float sqA[TILE], sqB[TILE];

    const int t  = threadIdx.x;
    const int bi = blockIdx.y, bj = blockIdx.x;
    const int kq   = t & 15;
    const int rsub = t >> 4;

    float4 lv = *reinterpret_cast<const float4*>(&l[kq * 4]);
    const float rlx = 1.f / lv.x, rly = 1.f / lv.y, rlz = 1.f / lv.z, rlw = 1.f / lv.w;
    const float* x1b = X1 + (size_t)(bi * TILE) * N_DIM;
    const float* x2b = X2 + (size_t)(bj * TILE) * N_DIM;

    #define STAGE(Xb, Th, Tl, SQ)                                              \
    {                                                                          \
        _Pragma("unroll")                                                      \
        for (int c = 0; c < 4; ++c) {                                          \
            const int row = c * 32 + rsub;                                     \
            float4 x = *reinterpret_cast<const float4*>(&(Xb)[row * N_DIM + kq * 4]); \
            float a0 = x.x * rlx, a1 = x.y * rly, a2 = x.z * rlz, a3 = x.w * rlw; \
            ushort_t h0 = f2bf(a0), h1 = f2bf(a1), h2 = f2bf(a2), h3 = f2bf(a3); \
            ushort_t e0 = f2bf(a0 - bf2f(h0)), e1 = f2bf(a1 - bf2f(h1));       \
            ushort_t e2 = f2bf(a2 - bf2f(h2)), e3 = f2bf(a3 - bf2f(h3));       \
            const int off = (row << 7) + (((kq >> 1) << 4) ^ ((row & 7) << 4)) + ((kq & 1) << 3); \
            uint2 hv, lvv;                                                     \
            hv.x  = (uint_t)h0 | ((uint_t)h1 << 16);                           \
            hv.y  = (uint_t)h2 | ((uint_t)h3 << 16);                           \
            lvv.x = (uint_t)e0 | ((uint_t)e1 << 16);                           \
            lvv.y = (uint_t)e2 | ((uint_t)e3 << 16);                           \
            *reinterpret_cast<uint2*>((char*)(Th) + off) = hv;                 \
            *reinterpret_cast<uint2*>((char*)(Tl) + off) = lvv;                \
            float s = a0 * a0;                                                 \
            s = fmaf(a1, a1, s); s = fmaf(a2, a2, s); s = fmaf(a3, a3, s);     \
            s += __shfl_xor(s, 1);                                             \
            s += __shfl_xor(s, 2);                                             \
            s += __shfl_xor(s, 4);                                             \
            s += __shfl_xor(s, 8);                                             \
            if (kq == 0) (SQ)[row] = s;                                        \
        }                                                                      \
    }
    STAGE(x1b, Ah, Al, sqA)
    STAGE(x2b, Bh, Bl, sqB)
    #undef STAGE
    __syncthreads();

    const int wid  = t >> 6;
    const int lane = t & 63;
    const int wtr = wid >> 1, wtc = wid & 1;
    const int fr  = lane & 15, kg = lane >> 4;

    f32x4 acc[2][4] = {};
    #pragma unroll
    for (int pass = 0; pass < 3; ++pass) {
        const ushort_t* TA = (pass == 2) ? Al : Ah;
        const ushort_t* TB = (pass == 1) ? Bl : Bh;
        #pragma unroll
        for (int kk = 0; kk < 2; ++kk) {
            s16x8 af[2], bg[4];
            #pragma unroll
            for (int m = 0; m < 2; ++m)
                af[m] = *reinterpret_cast<const s16x8*>(
                    (const char*)TA + swz16(wtr * 32 + m * 16 + fr, kk * 4 + kg));
            #pragma unroll
            for (int n = 0; n < 4; ++n)
                bg[n] = *reinterpret_cast<const s16x8*>(
                    (const char*)TB + swz16(wtc * 64 + n * 16 + fr, kk * 4 + kg));
            #pragma unroll
            for (int m = 0; m < 2; ++m)
                #pragma unroll
                for (int n = 0; n < 4; ++n)
                    acc[m][n] = __builtin_amdgcn_mfma_f32_16x16x32_bf16(
                        bg[n], af[m], acc[m][n], 0, 0, 0);
        }
    }

    const float c0 = cc[0];
    const float SQ5   = 2.23606797749979f;
    const float FIVE3 = 1.66666666666667f;
    const float lnc2  = 2.0f * __logf(c0);

    #pragma unroll
    for (int m = 0; m < 2; ++m) {
        const int row_l = wtr * 32 + m * 16 + fr;
        const float sa = sqA[row_l];
        float* rowp = out + ((size_t)(bi * TILE) + row_l) * (size_t)N2
                          + (size_t)(bj * TILE) + wtc * 64;
        #pragma unroll
        for (int n = 0; n < 4; ++n) {
            const int cb = n * 16 + kg * 4;
            f32x4 sb4 = *reinterpret_cast<const f32x4*>(&sqB[wtc * 64 + cb]);
            f32x4 v = acc[m][n];
            f32x4 res;
            #pragma unroll
            for (int q = 0; q < 4; ++q) {
                float d2 = fmaxf(fmaf(-2.0f, v[q], sa + sb4[q]), 0.0f);
                float r  = sqrtf(d2);
                float e  = __expf(fmaf(-SQ5, r, lnc2));
                res[q] = fmaf(FIVE3, d2, fmaf(SQ5, r, 1.0f)) * e;
            }
            *reinterpret_cast<f32x4*>(rowp + cb) = res;
        }
    }
}

extern "C" void kernel_launch(void* const* d_in, const int* in_sizes, int n_in,
                              void* d_out, int out_size, void* d_ws, size_t ws_size,
                              hipStream_t stream) {
    const float* X1 = (const float*)d_in[0];
    const float* X2 = (const float*)d_in[1];
    const float* c  = (const float*)d_in[2];
    const float* l  = (const float*)d_in[3];
    float* out = (float*)d_out;

    const int N1 = in_sizes[0] / N_DIM;   // 8192
    const int N2 = in_sizes[1] / N_DIM;   // 8192

    const size_t aBytes = (size_t)N1 * 128;
    const size_t bBytes = (size_t)N2 * 128;
    const size_t needWs = aBytes + bBytes + (size_t)(N1 + N2) * sizeof(float);

    const int nby  = N1 / TILE;           // 64
    const int nbx  = N2 / TILE;           // 64
    const int nblk = nby * nbx;           // 4096

    const bool shapeOK = (N1 % TILE == 0) && (N2 % TILE == 0) &&
                         (N1 % 16 == 0) && (nblk % 8 == 0);

    if (ws_size >= needWs && shapeOK) {
        unsigned char* A16 = (unsigned char*)d_ws;
        unsigned char* B16 = A16 + aBytes;
        float* sq1 = (float*)(B16 + bBytes);
        float* sq2 = sq1 + N1;

        matern52_prep_kernel<<<dim3((N1 + N2) / 16), 256, 0, stream>>>(
            X1, X2, l, A16, B16, sq1, sq2, N1);

        matern52_main_kernel<<<dim3(nblk), 256, 0, stream>>>(
            A16, B16, sq1, sq2, c, out, N1, N2, nbx, nblk / 8);
    } else {
        dim3 grid(N2 / TILE, N1 / TILE);
        matern52_fallback_kernel<<<grid, 512, 0, stream>>>(X1, X2, c, l, out, N1, N2);
    }
}

// Round 12
// 56.023 us; speedup vs baseline: 1.6354x; 1.0421x over previous
//
#include <hip/hip_runtime.h>
#include <math.h>

#define N_DIM 64
#define TILE  128

typedef unsigned short ushort_t;
typedef unsigned int   uint_t;
typedef _Float16 f16x8 __attribute__((ext_vector_type(8)));
typedef _Float16 f16x4 __attribute__((ext_vector_type(4)));
typedef float    f32x4 __attribute__((ext_vector_type(4)));

// Byte offset of 16B chunk kc (0..7) in row `row` of a [rows x 128B] tile,
// XOR-swizzled (G4): spreads 8 consecutive rows' same-kc chunks over 8 banksets.
__device__ __forceinline__ int swz16(int row, int kc) {
    return (row << 7) + ((kc ^ (row & 7)) << 4);
}

// global -> LDS direct copy, 16B per lane. LDS dest = wave-uniform base + lane*16.
typedef __attribute__((address_space(1))) const void gas_void;
typedef __attribute__((address_space(3))) void       las_void;
__device__ __forceinline__ void gload16(const void* g, void* l) {
    __builtin_amdgcn_global_load_lds((gas_void*)g, (las_void*)l, 16, 0, 0);
}

// ---------------------------------------------------------------------------
// Prep (X1 and X2 in ONE dispatch): X -> fp16(x/l), XOR-pre-permuted
// (linear global_load_lds + swizzled ds_read recovers source order —
// r5-verified), plus exact fp32 row norms.
// ---------------------------------------------------------------------------
__global__ __launch_bounds__(256)
void matern52_prep_kernel(const float* __restrict__ X1,
                          const float* __restrict__ X2,
                          const float* __restrict__ l,
                          unsigned char* __restrict__ dstA,
                          unsigned char* __restrict__ dstB,
                          float* __restrict__ sq1,
                          float* __restrict__ sq2,
                          int N1)
{
    const int t  = threadIdx.x;
    const int kq = t & 15;
    int row = blockIdx.x * 16 + (t >> 4);

    const float* __restrict__ X;
    unsigned char* __restrict__ dst;
    float* __restrict__ sq;
    if (row < N1) { X = X1; dst = dstA; sq = sq1; }
    else          { X = X2; dst = dstB; sq = sq2; row -= N1; }

    float4 lv = *reinterpret_cast<const float4*>(&l[kq * 4]);
    float4 x  = *reinterpret_cast<const float4*>(&X[(size_t)row * N_DIM + kq * 4]);
    const float a0 = x.x / lv.x, a1 = x.y / lv.y, a2 = x.z / lv.z, a3 = x.w / lv.w;

    float s = a0 * a0;
    s = fmaf(a1, a1, s); s = fmaf(a2, a2, s); s = fmaf(a3, a3, s);
    s += __shfl_xor(s, 1);
    s += __shfl_xor(s, 2);
    s += __shfl_xor(s, 4);
    s += __shfl_xor(s, 8);
    if (kq == 0) sq[row] = s;

    f16x4 h = { (_Float16)a0, (_Float16)a1, (_Float16)a2, (_Float16)a3 };
    const int off = (row << 7) + ((((kq >> 1) ^ (row & 7))) << 4) + ((kq & 1) << 3);
    *reinterpret_cast<f16x4*>(dst + off) = h;
}

// ---------------------------------------------------------------------------
// Main: r11 structure (256 thr = 4 waves 2x2, 128x128 tile, 32KB LDS,
// gload_lds staging, 1-pass K=64 fp16 MFMA operand-swapped, exp2 epilogue,
// chunked XCD swizzle, LDS-bounce transposed stores giving aligned 256B =
// 2 full 128B lines per 16-lane segment) + ONE change: NON-TEMPORAL stores.
// Theory: cached write-back sends the 256MB stream through L2 twice
// (fill-in + dirty eviction); the 7TB/s fill kernel streams past L2. NT on
// full-line-covered segments is RMW-free. r6's NT regression was NT on 64B
// half-lines + broken staging -- not a valid test of this mechanism.
// ---------------------------------------------------------------------------
__global__ __launch_bounds__(256, 4)
void matern52_main_kernel(const unsigned char* __restrict__ A16,
                          const unsigned char* __restrict__ B16,
                          const float* __restrict__ sq1,
                          const float* __restrict__ sq2,
                          const float* __restrict__ cc,
                          float* __restrict__ out,
                          int N1, int N2, int nbx, int chunk)
{
    __shared__ __align__(16) unsigned char lds[2 * TILE * N_DIM * 2]; // 32 KB

    const int t = threadIdx.x;

    // chunked XCD swizzle (bijective: nblk % 8 == 0 guaranteed by caller)
    const int orig  = blockIdx.x;
    const int newid = (orig & 7) * chunk + (orig >> 3);
    const int bi    = newid / nbx;
    const int bj    = newid % nbx;

    unsigned char* ldsA = lds;
    unsigned char* ldsB = lds + TILE * N_DIM * 2;

    // ---- stage: 8x global_load_lds dwordx4 per thread ----------------------
    {
        const unsigned char* srcA = A16 + (size_t)bi * (TILE * 128);
        const unsigned char* srcB = B16 + (size_t)bj * (TILE * 128);
        const int wbase = (t >> 6) << 10;       // wave-uniform LDS byte base
        const int gb    = t * 16;
        #pragma unroll
        for (int i = 0; i < 4; ++i) {
            gload16(srcA + i * 4096 + gb, ldsA + i * 4096 + wbase);
            gload16(srcB + i * 4096 + gb, ldsB + i * 4096 + wbase);
        }
    }
    __syncthreads();

    // ---- 1-pass fp16 MFMA, K=64 -------------------------------------------
    const int wid  = t >> 6;          // 0..3
    const int lane = t & 63;
    const int wtr  = wid >> 1;        // 0..1 : 64-row strip
    const int wtc  = wid & 1;         // 0..1 : 64-col strip
    const int fr   = lane & 15;
    const int kg   = lane >> 4;

    f32x4 acc[4][4] = {};

    #pragma unroll
    for (int kk = 0; kk < 2; ++kk) {
        f16x8 af[4], bg[4];
        #pragma unroll
        for (int m = 0; m < 4; ++m)
            af[m] = *reinterpret_cast<const f16x8*>(
                ldsA + swz16(wtr * 64 + m * 16 + fr, kk * 4 + kg));
        #pragma unroll
        for (int n = 0; n < 4; ++n)
            bg[n] = *reinterpret_cast<const f16x8*>(
                ldsB + swz16(wtc * 64 + n * 16 + fr, kk * 4 + kg));
        // swapped operands (r2-r5 verified): lane&15 -> out row, reg -> out col
        #pragma unroll
        for (int m = 0; m < 4; ++m)
            #pragma unroll
            for (int n = 0; n < 4; ++n)
                acc[m][n] = __builtin_amdgcn_mfma_f32_16x16x32_f16(
                    bg[n], af[m], acc[m][n], 0, 0, 0);
    }

    // all waves done with fragment ds_reads; staging LDS reusable as scratch
    __syncthreads();

    // ---- epilogue with LDS-bounce transposed NT stores ----------------------
    const float c0 = cc[0];
    const float SQ5   = 2.23606797749979f;
    const float FIVE3 = 1.66666666666667f;
    const float NK    = -3.22617785847899f;               // -sqrt5 * log2(e)
    const float l2c2  = 2.885390081777927f * __logf(c0);  // 2*log2(c0)

    const float* sqA = sq1 + bi * TILE;
    const float* sqB = sq2 + bj * TILE + wtc * 64;

    unsigned char* scr = lds + (wid << 12);   // 4 KB wave-private scratch

    f32x4 sb4[4];
    #pragma unroll
    for (int n = 0; n < 4; ++n)
        sb4[n] = *reinterpret_cast<const f32x4*>(sqB + n * 16 + kg * 4);

    const int r_off = lane >> 4;              // 0..3 : row sub-index on readback
    const int c16   = lane & 15;              // 16B column chunk on readback

    #pragma unroll
    for (int m = 0; m < 4; ++m) {
        const float sa = sqA[wtr * 64 + m * 16 + fr];

        // compute + scatter into scratch [16 rows][64 cols] f32, XOR-swizzled
        #pragma unroll
        for (int n = 0; n < 4; ++n) {
            f32x4 v = acc[m][n];
            f32x4 res;
            #pragma unroll
            for (int q = 0; q < 4; ++q) {
                float d2 = fmaxf(fmaf(-2.0f, v[q], sa + sb4[n][q]), 0.0f);
                float r  = __builtin_amdgcn_sqrtf(d2);               // raw v_sqrt_f32
                float e  = __builtin_amdgcn_exp2f(fmaf(NK, r, l2c2)); // raw v_exp_f32
                res[q] = fmaf(FIVE3, d2, fmaf(SQ5, r, 1.0f)) * e;
            }
            const int boff = (fr << 8) + ((((n << 6) + (kg << 4))) ^ ((fr & 7) << 4));
            *reinterpret_cast<f32x4*>(scr + boff) = res;
        }

        __builtin_amdgcn_wave_barrier();      // pin write->read order (HW DS in-order)

        // read back row-contiguous; NT store 4 rows x 256B (2 full lines each)
        #pragma unroll
        for (int i = 0; i < 4; ++i) {
            const int rr = i * 4 + r_off;     // 0..15
            const int rb = (rr << 8) + ((c16 << 4) ^ ((rr & 7) << 4));
            f32x4 val = *reinterpret_cast<const f32x4*>(scr + rb);
            const int grow = wtr * 64 + m * 16 + rr;
            float* p = out + ((size_t)(bi * TILE) + grow) * (size_t)N2
                           + (size_t)(bj * TILE) + wtc * 64 + c16 * 4;
            __builtin_nontemporal_store(val, reinterpret_cast<f32x4*>(p));
        }

        __builtin_amdgcn_wave_barrier();      // reads of m before writes of m+1
    }
}

// ---------------------------------------------------------------------------
// Fallback (ws too small / odd shapes): self-contained split-bf16 (r3-verified).
// ---------------------------------------------------------------------------
__device__ __forceinline__ ushort_t f2bf(float f) {
    uint_t u = __float_as_uint(f);
    u += 0x7FFFu + ((u >> 16) & 1u);
    return (ushort_t)(u >> 16);
}
__device__ __forceinline__ float bf2f(ushort_t h) {
    return __uint_as_float(((uint_t)h) << 16);
}
typedef short s16x8 __attribute__((ext_vector_type(8)));

__global__ __launch_bounds__(512, 4)
void matern52_fallback_kernel(const float* __restrict__ X1,
                              const float* __restrict__ X2,
                              const float* __restrict__ cc,
                              const float* __restrict__ l,
                              float* __restrict__ out,
                              int N1, int N2)
{
    __shared__ ushort_t Ah[TILE * N_DIM], Al[TILE * N_DIM];
    __shared__ ushort_t Bh[TILE * N_DIM], Bl[TILE * N_DIM];
    __shared__ float sqA[TILE], sqB[TILE];

    const int t  = threadIdx.x;
    const int bi = blockIdx.y, bj = blockIdx.x;
    const int kq   = t & 15;
    const int rsub = t >> 4;

    float4 lv = *reinterpret_cast<const float4*>(&l[kq * 4]);
    const float rlx = 1.f / lv.x, rly = 1.f / lv.y, rlz = 1.f / lv.z, rlw = 1.f / lv.w;
    const float* x1b = X1 + (size_t)(bi * TILE) * N_DIM;
    const float* x2b = X2 + (size_t)(bj * TILE) * N_DIM;

    #define STAGE(Xb, Th, Tl, SQ)                                              \
    {                                                                          \
        _Pragma("unroll")                                                      \
        for (int c = 0; c < 4; ++c) {                                          \
            const int row = c * 32 + rsub;                                     \
            float4 x = *reinterpret_cast<const float4*>(&(Xb)[row * N_DIM + kq * 4]); \
            float a0 = x.x * rlx, a1 = x.y * rly, a2 = x.z * rlz, a3 = x.w * rlw; \
            ushort_t h0 = f2bf(a0), h1 = f2bf(a1), h2 = f2bf(a2), h3 = f2bf(a3); \
            ushort_t e0 = f2bf(a0 - bf2f(h0)), e1 = f2bf(a1 - bf2f(h1));       \
            ushort_t e2 = f2bf(a2 - bf2f(h2)), e3 = f2bf(a3 - bf2f(h3));       \
            const int off = (row << 7) + (((kq >> 1) << 4) ^ ((row & 7) << 4)) + ((kq & 1) << 3); \
            uint2 hv, lvv;                                                     \
            hv.x  = (uint_t)h0 | ((uint_t)h1 << 16);                           \
            hv.y  = (uint_t)h2 | ((uint_t)h3 << 16);                           \
            lvv.x = (uint_t)e0 | ((uint_t)e1 << 16);                           \
            lvv.y = (uint_t)e2 | ((uint_t)e3 << 16);                           \
            *reinterpret_cast<uint2*>((char*)(Th) + off) = hv;                 \
            *reinterpret_cast<uint2*>((char*)(Tl) + off) = lvv;                \
            float s = a0 * a0;                                                 \
            s = fmaf(a1, a1, s); s = fmaf(a2, a2, s); s = fmaf(a3, a3, s);     \
            s += __shfl_xor(s, 1);                                             \
            s += __shfl_xor(s, 2);                                             \
            s += __shfl_xor(s, 4);                                             \
            s += __shfl_xor(s, 8);                                             \
            if (kq == 0) (SQ)[row] = s;                                        \
        }                                                                      \
    }
    STAGE(x1b, Ah, Al, sqA)
    STAGE(x2b, Bh, Bl, sqB)
    #undef STAGE
    __syncthreads();

    const int wid  = t >> 6;
    const int lane = t & 63;
    const int wtr = wid >> 1, wtc = wid & 1;
    const int fr  = lane & 15, kg = lane >> 4;

    f32x4 acc[2][4] = {};
    #pragma unroll
    for (int pass = 0; pass < 3; ++pass) {
        const ushort_t* TA = (pass == 2) ? Al : Ah;
        const ushort_t* TB = (pass == 1) ? Bl : Bh;
        #pragma unroll
        for (int kk = 0; kk < 2; ++kk) {
            s16x8 af[2], bg[4];
            #pragma unroll
            for (int m = 0; m < 2; ++m)
                af[m] = *reinterpret_cast<const s16x8*>(
                    (const char*)TA + swz16(wtr * 32 + m * 16 + fr, kk * 4 + kg));
            #pragma unroll
            for (int n = 0; n < 4; ++n)
                bg[n] = *reinterpret_cast<const s16x8*>(
                    (const char*)TB + swz16(wtc * 64 + n * 16 + fr, kk * 4 + kg));
            #pragma unroll
            for (int m = 0; m < 2; ++m)
                #pragma unroll
                for (int n = 0; n < 4; ++n)
                    acc[m][n] = __builtin_amdgcn_mfma_f32_16x16x32_bf16(
                        bg[n], af[m], acc[m][n], 0, 0, 0);
        }
    }

    const float c0 = cc[0];
    const float SQ5   = 2.23606797749979f;
    const float FIVE3 = 1.66666666666667f;
    const float lnc2  = 2.0f * __logf(c0);

    #pragma unroll
    for (int m = 0; m < 2; ++m) {
        const int row_l = wtr * 32 + m * 16 + fr;
        const float sa = sqA[row_l];
        float* rowp = out + ((size_t)(bi * TILE) + row_l) * (size_t)N2
                          + (size_t)(bj * TILE) + wtc * 64;
        #pragma unroll
        for (int n = 0; n < 4; ++n) {
            const int cb = n * 16 + kg * 4;
            f32x4 sb4 = *reinterpret_cast<const f32x4*>(&sqB[wtc * 64 + cb]);
            f32x4 v = acc[m][n];
            f32x4 res;
            #pragma unroll
            for (int q = 0; q < 4; ++q) {
                float d2 = fmaxf(fmaf(-2.0f, v[q], sa + sb4[q]), 0.0f);
                float r  = sqrtf(d2);
                float e  = __expf(fmaf(-SQ5, r, lnc2));
                res[q] = fmaf(FIVE3, d2, fmaf(SQ5, r, 1.0f)) * e;
            }
            *reinterpret_cast<f32x4*>(rowp + cb) = res;
        }
    }
}

extern "C" void kernel_launch(void* const* d_in, const int* in_sizes, int n_in,
                              void* d_out, int out_size, void* d_ws, size_t ws_size,
                              hipStream_t stream) {
    const float* X1 = (const float*)d_in[0];
    const float* X2 = (const float*)d_in[1];
    const float* c  = (const float*)d_in[2];
    const float* l  = (const float*)d_in[3];
    float* out = (float*)d_out;

    const int N1 = in_sizes[0] / N_DIM;   // 8192
    const int N2 = in_sizes[1] / N_DIM;   // 8192

    const size_t aBytes = (size_t)N1 * 128;
    const size_t bBytes = (size_t)N2 * 128;
    const size_t needWs = aBytes + bBytes + (size_t)(N1 + N2) * sizeof(float);

    const int nby  = N1 / TILE;           // 64
    const int nbx  = N2 / TILE;           // 64
    const int nblk = nby * nbx;           // 4096

    const bool shapeOK = (N1 % TILE == 0) && (N2 % TILE == 0) &&
                         (N1 % 16 == 0) && (nblk % 8 == 0);

    if (ws_size >= needWs && shapeOK) {
        unsigned char* A16 = (unsigned char*)d_ws;
        unsigned char* B16 = A16 + aBytes;
        float* sq1 = (float*)(B16 + bBytes);
        float* sq2 = sq1 + N1;

        matern52_prep_kernel<<<dim3((N1 + N2) / 16), 256, 0, stream>>>(
            X1, X2, l, A16, B16, sq1, sq2, N1);

        matern52_main_kernel<<<dim3(nblk), 256, 0, stream>>>(
            A16, B16, sq1, sq2, c, out, N1, N2, nbx, nblk / 8);
    } else {
        dim3 grid(N2 / TILE, N1 / TILE);
        matern52_fallback_kernel<<<grid, 512, 0, stream>>>(X1, X2, c, l, out, N1, N2);
    }
}